// Round 17
// baseline (335.935 us; speedup 1.0000x reference)
//
#include <hip/hip_runtime.h>

typedef _Float16 f16;
typedef _Float16 f16x8 __attribute__((ext_vector_type(8)));
typedef __fp16 fp16x2 __attribute__((ext_vector_type(2)));
typedef float f32x4 __attribute__((ext_vector_type(4)));

#define CDIM 256
#define NPIX 9216
#define NB 8

__device__ __forceinline__ f32x4 mfma16(f16x8 a, f16x8 b, f32x4 c) {
  return __builtin_amdgcn_mfma_f32_16x16x32_f16(a, b, c, 0, 0, 0);
}
__device__ __forceinline__ f16x8 ld8(const f16* p) { return *(const f16x8*)p; }

__device__ __forceinline__ void stage16(const void* g, void* l) {
  __builtin_amdgcn_global_load_lds((const __attribute__((address_space(1))) unsigned int*)g,
                                   (__attribute__((address_space(3))) unsigned int*)l, 16, 0, 0);
}
#define S_BARRIER() do { asm volatile("" ::: "memory"); __builtin_amdgcn_s_barrier(); asm volatile("" ::: "memory"); } while (0)
#define WAIT_VM(N) do { asm volatile("s_waitcnt vmcnt(" #N ")" ::: "memory"); __builtin_amdgcn_sched_barrier(0); } while (0)

__device__ __forceinline__ unsigned pkrtz(float a, float b) {
  union { fp16x2 h; unsigned u; } cv;
  cv.h = __builtin_amdgcn_cvt_pkrtz(a, b);
  return cv.u;
}
union U8 { f16x8 v; unsigned u[4]; };
__device__ __forceinline__ f16x8 mk8(unsigned a, unsigned b, unsigned c, unsigned d) {
  U8 r; r.u[0] = a; r.u[1] = b; r.u[2] = c; r.u[3] = d; return r.v;
}

// 16x16x32 frags (HW-verified): A: lane(l15,q) holds A[row=l15][k=8q+e].
// B: B[k=8q+e][col=l15].  D: col=l15, row=4q+r.  1KB lane-linear frags.
// Permutation trick (verified R13): slot(q,e) <-> 16*(e>>2)+4q+(e&3) for both
// PV keys and QK chans -> zero-shuffle S->P packing. K/V/Wq producers write
// these layouts.

// ---------------- K1: fold weights; Wq/Wk2/Wv2 all frag-linear 16x16 ----------------
// frag(fr = o>>4, sp = c>>5): lane = 16*((c>>3)&3) + (o&15), elem e = c&7.
__global__ void prep_weights(const float* __restrict__ Wq,
                             const float* __restrict__ Wk, const float* __restrict__ bk,
                             const float* __restrict__ Wv, const float* __restrict__ bv,
                             const float* __restrict__ Ws, const float* __restrict__ bs,
                             f16* __restrict__ WqF, f16* __restrict__ WkF, f16* __restrict__ WvF,
                             float* __restrict__ bk2, float* __restrict__ bv2) {
  int o = blockIdx.x, c = threadIdx.x;
  float ak = 0.f, av = 0.f;
  for (int i = 0; i < CDIM; ++i) {
    float w = Ws[o*CDIM + i];
    ak += w * Wk[i*CDIM + c];
    av += w * Wv[i*CDIM + c];
  }
  {
    size_t fbyte = (size_t)((o >> 4)*8 + (c >> 5))*1024
                 + (size_t)(16*((c >> 3) & 3) + (o & 15))*16 + (c & 7)*2;
    *(f16*)((char*)WqF + fbyte) = (f16)Wq[o*CDIM + c];
    *(f16*)((char*)WkF + fbyte) = (f16)ak;
    *(f16*)((char*)WvF + fbyte) = (f16)av;
  }
  if (c == 0) {
    float sk = 0.f, sv = 0.f;
    for (int i = 0; i < CDIM; ++i) { float w = Ws[o*CDIM + i]; sk += w*bk[i]; sv += w*bv[i]; }
    bk2[o] = sk + bs[o];
    bv2[o] = sv + bs[o];
  }
}

// ---------------- K2: x[b][c][n] f32 -> xT swizzled [b][n][c] f16 ----------------
__global__ void transpose_x(const float* __restrict__ x, char* __restrict__ xT) {
  __shared__ f16 tile[32][34];   // [c][n]
  int c0 = blockIdx.x * 32, n0 = blockIdx.y * 32, b = blockIdx.z;
  int tx = threadIdx.x, ty = threadIdx.y;
#pragma unroll
  for (int j = 0; j < 4; ++j) {
    int cl = ty + 8*j;
    tile[cl][tx] = (f16)x[(size_t)(b*CDIM + c0 + cl)*NPIX + n0 + tx];
  }
  __syncthreads();
  int tid = ty*32 + tx;
  if (tid < 128) {
    int nl = tid >> 2, u = tid & 3;
    int n = n0 + nl;
    int cu = (c0 >> 3) + u;
    f16x8 v;
#pragma unroll
    for (int e = 0; e < 8; ++e) v[e] = tile[8*u + e][nl];
    size_t byte = (size_t)(b*NPIX + n)*512 + (size_t)((cu ^ (n & 7)) << 4);
    *(f16x8*)(xT + byte) = v;
  }
}

// ---------------- K3: K/V at subsampled pixels -> permuted 16x16-frag chunks ----------------
// kB per (b,tile): 16KB; frag f=2s+kt: K[key-half kt][ch-slice s] (slot perm).
// vB per (b,tile): 16KB; frag cg: V[c=16cg+..][key slot perm].
__global__ __launch_bounds__(256) void compute_kv(
    const char* __restrict__ xT, const f16* __restrict__ WkF, const f16* __restrict__ WvF,
    const float* __restrict__ bk2, const float* __restrict__ bv2,
    char* __restrict__ kB, char* __restrict__ vB) {
  int ch = blockIdx.x;            // key tile (32 keys)
  int m0 = ch * 32;
  int b = blockIdx.y;
  int tid = threadIdx.x;
  int w = tid >> 6, lane = tid & 63, l15 = lane & 15, q = lane >> 4;
  size_t chbase = (size_t)(b*32 + ch)*16384;

  const char* xrow[2]; int xn7[2];
#pragma unroll
  for (int mt2 = 0; mt2 < 2; ++mt2) {
    int m = m0 + 16*mt2 + l15;
    int n = 288*(m >> 5) + 3*(m & 31);   // subsampled pixel index
    xrow[mt2] = xT + (size_t)(b*NPIX + n)*512;
    xn7[mt2] = n & 7;
  }
  const char* wkf = (const char*)WkF + (size_t)lane*16;
  const char* wvf = (const char*)WvF + (size_t)lane*16;

  f32x4 accK[2][4] = {};
  f32x4 accV[4][2] = {};
  for (int ks = 0; ks < 8; ++ks) {
    f16x8 am[2], wk[4], wv[4];
#pragma unroll
    for (int mt2 = 0; mt2 < 2; ++mt2)
      am[mt2] = *(const f16x8*)(xrow[mt2] + (((q + 4*ks) ^ xn7[mt2]) << 4));
#pragma unroll
    for (int t = 0; t < 4; ++t) {
      wk[t] = *(const f16x8*)(wkf + (size_t)((4*w + t)*8 + ks)*1024);
      wv[t] = *(const f16x8*)(wvf + (size_t)((4*w + t)*8 + ks)*1024);
    }
#pragma unroll
    for (int mt2 = 0; mt2 < 2; ++mt2)
#pragma unroll
      for (int ot = 0; ot < 4; ++ot) {
        accK[mt2][ot] = mfma16(am[mt2], wk[ot], accK[mt2][ot]);   // D[m][o]
        accV[ot][mt2] = mfma16(wv[ot], am[mt2], accV[ot][mt2]);   // D[c][m]
      }
  }
  // K writes (R13 permuted format): keyrel=16mt2+4q+r, cin=64w+16ot+l15
#pragma unroll
  for (int mt2 = 0; mt2 < 2; ++mt2)
#pragma unroll
    for (int ot = 0; ot < 4; ++ot) {
      int cin = 64*w + 16*ot + l15;
      float bo = bk2[cin];
      int f = 2*(cin >> 5) + mt2;
      int q_s = (cin >> 2) & 3;
      int e_s = 4*((cin >> 4) & 1) + (cin & 3);
      size_t fb = chbase + (size_t)f*1024 + (size_t)(16*q_s)*16 + e_s*2;
#pragma unroll
      for (int r = 0; r < 4; ++r) {
        int krel15 = 4*q + r;
        *(f16*)(kB + fb + (size_t)krel15*16) = (f16)(accK[mt2][ot][r] + bo);
      }
    }
  // V writes (R13 permuted format): c=64w+16ct+4q+r, keyrel=16mt2+l15
#pragma unroll
  for (int ct = 0; ct < 4; ++ct) {
    f32x4 bv4 = *(const f32x4*)(bv2 + 64*w + 16*ct + 4*q);
#pragma unroll
    for (int mt2 = 0; mt2 < 2; ++mt2) {
      int q_s = (l15 >> 2) & 3;
      int e_s = 4*mt2 + (l15 & 3);
#pragma unroll
      for (int r = 0; r < 4; ++r) {
        int c = 64*w + 16*ct + 4*q + r;
        size_t byte = chbase + (size_t)(c >> 4)*1024
                    + (size_t)(16*q_s + (c & 15))*16 + e_s*2;
        *(f16*)(vB + byte) = (f16)(accV[ct][mt2][r] + bv4[r]);
      }
    }
  }
}

// ---------------- K4: attention, dual-stream 16x16 (2 independent 16-row groups/wave) ----
// 4 waves x 32 rows = 128 rows/block, 576 blocks (8 x 72). Groups share all
// K/V frag reads; two independent QK->softmax->PV streams interleave.
__global__ __launch_bounds__(256, 2) void attention(
    const char* __restrict__ xT, const f16* __restrict__ WqF, const float* __restrict__ bq,
    const char* __restrict__ kB, const char* __restrict__ vB,
    const float* __restrict__ xg, const float* __restrict__ gamma_p,
    float* __restrict__ out) {
  __shared__ char lds[65536];    // [2][ K 16KB | V 16KB ]

  int bid = blockIdx.x;
  int b = bid & 7;               // XCD-bijective: 576 = 8*72
  int tile = bid >> 3;
  int tid = threadIdx.x;
  int w = tid >> 6, lane = tid & 63, l15 = lane & 15, q = lane >> 4;
  int n0w = tile*128 + w*32;     // wave rows: group g covers n0w+16g+l15
  int lane16 = lane * 16;

  const char* kBb = kB + (size_t)b*524288;
  const char* vBb = vB + (size_t)b*524288;

  // ---- stage K0/V0 (hidden under Q build) ----
  {
    int so = tid * 16;
#pragma unroll
    for (int r = 0; r < 4; ++r) stage16(kBb + so + r*4096, lds + so + r*4096);
#pragma unroll
    for (int r = 0; r < 4; ++r) stage16(vBb + so + r*4096, lds + 16384 + so + r*4096);
  }

  // ---- Q build per group (R13 pattern, zero-shuffle pack) ----
  f16x8 qf[2][8];
#pragma unroll
  for (int g = 0; g < 2; ++g) {
    f16x8 xb[8];
    int n = n0w + 16*g + l15;
    const char* xrow = xT + (size_t)(b*NPIX + n)*512;
    int n7 = n & 7;
#pragma unroll
    for (int sp = 0; sp < 8; ++sp)
      xb[sp] = *(const f16x8*)(xrow + (((4*sp + q) ^ n7) << 4));
    f32x4 qacc[16];
#pragma unroll
    for (int og = 0; og < 16; ++og) {
      f32x4 acc = {0.f, 0.f, 0.f, 0.f};
#pragma unroll
      for (int sp = 0; sp < 8; ++sp) {
        f16x8 wa = *(const f16x8*)((const char*)WqF + (size_t)(og*8 + sp)*1024 + lane16);
        acc = mfma16(wa, xb[sp], acc);       // D[o_rel=4q+r][row=l15]
      }
      f32x4 bq4 = *(const f32x4*)(bq + og*16 + 4*q);
#pragma unroll
      for (int r = 0; r < 4; ++r) acc[r] += bq4[r];
      qacc[og] = acc;
    }
#pragma unroll
    for (int s = 0; s < 8; ++s)
      qf[g][s] = mk8(pkrtz(qacc[2*s][0],   qacc[2*s][1]),
                     pkrtz(qacc[2*s][2],   qacc[2*s][3]),
                     pkrtz(qacc[2*s+1][0], qacc[2*s+1][1]),
                     pkrtz(qacc[2*s+1][2], qacc[2*s+1][3]));
  }

  // ---- main loop: 32 key-tiles, K/V dbuf, counted vmcnt ----
  f32x4 OA[16], OB[16];
#pragma unroll
  for (int i = 0; i < 16; ++i) {
    OA[i] = (f32x4){0.f, 0.f, 0.f, 0.f};
    OB[i] = (f32x4){0.f, 0.f, 0.f, 0.f};
  }
  float mA = -3e38f, lA = 0.f;
  float mB = -3e38f, lB = 0.f;

  for (int t = 0; t < 32; ++t) {
    char* curb = lds + ((t & 1) << 15);
    if (t < 31) {
      const char* ksrc = kBb + (size_t)(t + 1)*16384;
      const char* vsrc = vBb + (size_t)(t + 1)*16384;
      char* kd = lds + (((t + 1) & 1) << 15);
      int so = tid * 16;
#pragma unroll
      for (int r = 0; r < 4; ++r) stage16(ksrc + so + r*4096, kd + so + r*4096);
#pragma unroll
      for (int r = 0; r < 4; ++r) stage16(vsrc + so + r*4096, kd + 16384 + so + r*4096);
      WAIT_VM(8);
    } else {
      WAIT_VM(0);
    }
    S_BARRIER();

    // QK^T both groups, shared kf reads; 4 independent 8-deep chains
    f32x4 SA0 = {0.f,0.f,0.f,0.f}, SA1 = {0.f,0.f,0.f,0.f};
    f32x4 SB0 = {0.f,0.f,0.f,0.f}, SB1 = {0.f,0.f,0.f,0.f};
    __builtin_amdgcn_s_setprio(1);
#pragma unroll
    for (int s = 0; s < 8; ++s) {
      f16x8 kf0 = *(const f16x8*)(curb + (2*s)*1024 + lane16);
      SA0 = mfma16(kf0, qf[0][s], SA0);
      SB0 = mfma16(kf0, qf[1][s], SB0);
      f16x8 kf1 = *(const f16x8*)(curb + (2*s + 1)*1024 + lane16);
      SA1 = mfma16(kf1, qf[0][s], SA1);
      SB1 = mfma16(kf1, qf[1][s], SB1);
    }
    __builtin_amdgcn_s_setprio(0);

    // ---- softmax A ----
    float mxA = fmaxf(fmaxf(fmaxf(SA0[0], SA0[1]), fmaxf(SA0[2], SA0[3])),
                      fmaxf(fmaxf(SA1[0], SA1[1]), fmaxf(SA1[2], SA1[3])));
    mxA = fmaxf(mxA, __shfl_xor(mxA, 16));
    mxA = fmaxf(mxA, __shfl_xor(mxA, 32));
    if (!__all(mxA <= mA + 8.0f)) {       // T13 defer-max
      float mn = fmaxf(mA, mxA);
      float al = __expf(mA - mn);
      mA = mn;
      lA *= al;
#pragma unroll
      for (int i = 0; i < 16; ++i)
#pragma unroll
        for (int r = 0; r < 4; ++r) OA[i][r] *= al;
    }
    float lsA = 0.f;
#pragma unroll
    for (int r = 0; r < 4; ++r) { SA0[r] = __expf(SA0[r] - mA); lsA += SA0[r]; }
#pragma unroll
    for (int r = 0; r < 4; ++r) { SA1[r] = __expf(SA1[r] - mA); lsA += SA1[r]; }
    lA += lsA;
    f16x8 pfA = mk8(pkrtz(SA0[0], SA0[1]), pkrtz(SA0[2], SA0[3]),
                    pkrtz(SA1[0], SA1[1]), pkrtz(SA1[2], SA1[3]));

    // ---- softmax B ----
    float mxB = fmaxf(fmaxf(fmaxf(SB0[0], SB0[1]), fmaxf(SB0[2], SB0[3])),
                      fmaxf(fmaxf(SB1[0], SB1[1]), fmaxf(SB1[2], SB1[3])));
    mxB = fmaxf(mxB, __shfl_xor(mxB, 16));
    mxB = fmaxf(mxB, __shfl_xor(mxB, 32));
    if (!__all(mxB <= mB + 8.0f)) {
      float mn = fmaxf(mB, mxB);
      float al = __expf(mB - mn);
      mB = mn;
      lB *= al;
#pragma unroll
      for (int i = 0; i < 16; ++i)
#pragma unroll
        for (int r = 0; r < 4; ++r) OB[i][r] *= al;
    }
    float lsB = 0.f;
#pragma unroll
    for (int r = 0; r < 4; ++r) { SB0[r] = __expf(SB0[r] - mB); lsB += SB0[r]; }
#pragma unroll
    for (int r = 0; r < 4; ++r) { SB1[r] = __expf(SB1[r] - mB); lsB += SB1[r]; }
    lB += lsB;
    f16x8 pfB = mk8(pkrtz(SB0[0], SB0[1]), pkrtz(SB0[2], SB0[3]),
                    pkrtz(SB1[0], SB1[1]), pkrtz(SB1[2], SB1[3]));

    // ---- PV both groups, shared vf reads ----
    __builtin_amdgcn_s_setprio(1);
#pragma unroll
    for (int cg = 0; cg < 16; ++cg) {
      f16x8 vf = *(const f16x8*)(curb + 16384 + cg*1024 + lane16);
      OA[cg] = mfma16(vf, pfA, OA[cg]);
      OB[cg] = mfma16(vf, pfB, OB[cg]);
    }
    __builtin_amdgcn_s_setprio(0);
    S_BARRIER();
  }

  // ---- epilogue per group: out = gamma*O/l + x ----
  float g = gamma_p[0];
  lA += __shfl_xor(lA, 16);
  lA += __shfl_xor(lA, 32);
  lB += __shfl_xor(lB, 16);
  lB += __shfl_xor(lB, 32);
  float invA = 1.0f / lA, invB = 1.0f / lB;
  int nA = n0w + l15, nB = n0w + 16 + l15;
#pragma unroll
  for (int cg = 0; cg < 16; ++cg)
#pragma unroll
    for (int r = 0; r < 4; ++r) {
      int c = 16*cg + 4*q + r;
      size_t rowbase = (size_t)(b*CDIM + c)*NPIX;
      out[rowbase + nA] = g * (OA[cg][r] * invA) + xg[rowbase + nA];
      out[rowbase + nB] = g * (OB[cg][r] * invB) + xg[rowbase + nB];
    }
}

extern "C" void kernel_launch(void* const* d_in, const int* in_sizes, int n_in,
                              void* d_out, int out_size, void* d_ws, size_t ws_size,
                              hipStream_t stream) {
  (void)in_sizes; (void)n_in; (void)out_size; (void)ws_size;
  const float* x     = (const float*)d_in[0];
  const float* Wq    = (const float*)d_in[1];
  const float* bq    = (const float*)d_in[2];
  const float* Wk    = (const float*)d_in[3];
  const float* bk    = (const float*)d_in[4];
  const float* Wv    = (const float*)d_in[5];
  const float* bv    = (const float*)d_in[6];
  const float* Ws    = (const float*)d_in[7];
  const float* bs    = (const float*)d_in[8];
  const float* gamma = (const float*)d_in[9];

  char* ws = (char*)d_ws;
  float* bk2 = (float*)(ws);
  float* bv2 = (float*)(ws + 1024);
  char* xT   = ws + 4096;
  char* kB   = ws + 4096 + 37748736;
  char* vB   = kB + 4194304;
  f16* WqF   = (f16*)(vB + 4194304);
  f16* WkF   = WqF + 65536;
  f16* WvF   = WkF + 65536;

  prep_weights<<<256, 256, 0, stream>>>(Wq, Wk, bk, Wv, bv, Ws, bs, WqF, WkF, WvF, bk2, bv2);
  transpose_x<<<dim3(8, 288, 8), dim3(32, 8), 0, stream>>>(x, xT);
  compute_kv<<<dim3(32, 8), 256, 0, stream>>>(xT, WkF, WvF, bk2, bv2, kB, vB);
  attention<<<576, 256, 0, stream>>>(xT, WqF, bq, kB, vB, x, gamma, (float*)d_out);
}

// Round 18
// 195.326 us; speedup vs baseline: 1.7199x; 1.7199x over previous
//
#include <hip/hip_runtime.h>

typedef _Float16 f16;
typedef _Float16 f16x8 __attribute__((ext_vector_type(8)));
typedef __fp16 fp16x2 __attribute__((ext_vector_type(2)));
typedef float f32x4 __attribute__((ext_vector_type(4)));
typedef float f32x16 __attribute__((ext_vector_type(16)));

#define CDIM 256
#define NPIX 9216
#define NB 8

__device__ __forceinline__ f32x4 mfma16(f16x8 a, f16x8 b, f32x4 c) {
  return __builtin_amdgcn_mfma_f32_16x16x32_f16(a, b, c, 0, 0, 0);
}
__device__ __forceinline__ f32x16 mfma32(f16x8 a, f16x8 b, f32x16 c) {
  return __builtin_amdgcn_mfma_f32_32x32x16_f16(a, b, c, 0, 0, 0);
}
__device__ __forceinline__ f16x8 ld8(const f16* p) { return *(const f16x8*)p; }

__device__ __forceinline__ void stage16(const void* g, void* l) {
  __builtin_amdgcn_global_load_lds((const __attribute__((address_space(1))) unsigned int*)g,
                                   (__attribute__((address_space(3))) unsigned int*)l, 16, 0, 0);
}
#define S_BARRIER() do { asm volatile("" ::: "memory"); __builtin_amdgcn_s_barrier(); asm volatile("" ::: "memory"); } while (0)
#define WAIT_VM(N) do { asm volatile("s_waitcnt vmcnt(" #N ")" ::: "memory"); __builtin_amdgcn_sched_barrier(0); } while (0)

__device__ __forceinline__ unsigned pkrtz(float a, float b) {
  union { fp16x2 h; unsigned u; } cv;
  cv.h = __builtin_amdgcn_cvt_pkrtz(a, b);
  return cv.u;
}
union U8 { f16x8 v; unsigned u[4]; };

// Pack 8 f32 (reg-order of a 32x32 D half-group) into f16x8 B-frag word order,
// exchanging quads with the lane^32 partner via shfl (verified R9).
__device__ __forceinline__ f16x8 pack_swap(float v0, float v1, float v2, float v3,
                                           float v4, float v5, float v6, float v7,
                                           int hh) {
  unsigned a  = pkrtz(v0, v1);
  unsigned b2 = pkrtz(v2, v3);
  unsigned c2 = pkrtz(v4, v5);
  unsigned d2 = pkrtz(v6, v7);
  unsigned ex1 = __shfl_xor(hh ? a : c2, 32);
  unsigned ex2 = __shfl_xor(hh ? b2 : d2, 32);
  U8 r;
  r.u[0] = hh ? ex1 : a;
  r.u[1] = hh ? ex2 : b2;
  r.u[2] = hh ? c2 : ex1;
  r.u[3] = hh ? d2 : ex2;
  return r.v;
}

// 32x32x16 frags: A: lane(l31,h) holds A[row=l31][k=8h+e]; B: B[k=8h+e][col=l31].
// D: col=lane&31, row=(reg&3)+8*(reg>>2)+4*(lane>>5). 1KB lane-linear frags.
// 16x16x32 frags (K3): A: lane(l15,q)=lane 16q+l15 holds A[row=l15][k=8q+e];
// B: B[k=8q+e][col=l15]; identical lane layout -> one buffer serves both roles.

// ---------------- K1: fold weights; ALL weights as frag-linear layouts ----------------
// frag(fr = o>>4, sp = c>>5): lane = 16*((c>>3)&3) + (o&15), elem e = c&7.
__global__ void prep_weights(const float* __restrict__ Wq,
                             const float* __restrict__ Wk, const float* __restrict__ bk,
                             const float* __restrict__ Wv, const float* __restrict__ bv,
                             const float* __restrict__ Ws, const float* __restrict__ bs,
                             f16* __restrict__ WqF, f16* __restrict__ WkF, f16* __restrict__ WvF,
                             float* __restrict__ bk2, float* __restrict__ bv2) {
  int o = blockIdx.x, c = threadIdx.x;
  float ak = 0.f, av = 0.f;
  for (int i = 0; i < CDIM; ++i) {
    float w = Ws[o*CDIM + i];
    ak += w * Wk[i*CDIM + c];
    av += w * Wv[i*CDIM + c];
  }
  {
    // WqF uses the 32x32-A layout (K4 Q build), verified R9:
    size_t qbyte = (size_t)((o >> 5)*16 + (c >> 4))*1024
                 + (size_t)(((c >> 3) & 1)*32 + (o & 31))*16 + (c & 7)*2;
    *(f16*)((char*)WqF + qbyte) = (f16)Wq[o*CDIM + c];
    // WkF/WvF use the 16x16 frag-linear layout (K3):
    size_t fbyte = (size_t)((o >> 4)*8 + (c >> 5))*1024
                 + (size_t)(16*((c >> 3) & 3) + (o & 15))*16 + (c & 7)*2;
    *(f16*)((char*)WkF + fbyte) = (f16)ak;
    *(f16*)((char*)WvF + fbyte) = (f16)av;
  }
  if (c == 0) {
    float sk = 0.f, sv = 0.f;
    for (int i = 0; i < CDIM; ++i) { float w = Ws[o*CDIM + i]; sk += w*bk[i]; sv += w*bv[i]; }
    bk2[o] = sk + bs[o];
    bv2[o] = sv + bs[o];
  }
}

// ---------------- K2: x[b][c][n] f32 -> xT swizzled [b][n][c] f16 ----------------
__global__ void transpose_x(const float* __restrict__ x, char* __restrict__ xT) {
  __shared__ f16 tile[32][34];   // [c][n]
  int c0 = blockIdx.x * 32, n0 = blockIdx.y * 32, b = blockIdx.z;
  int tx = threadIdx.x, ty = threadIdx.y;
#pragma unroll
  for (int j = 0; j < 4; ++j) {
    int cl = ty + 8*j;
    tile[cl][tx] = (f16)x[(size_t)(b*CDIM + c0 + cl)*NPIX + n0 + tx];
  }
  __syncthreads();
  int tid = ty*32 + tx;
  if (tid < 128) {
    int nl = tid >> 2, u = tid & 3;
    int n = n0 + nl;
    int cu = (c0 >> 3) + u;
    f16x8 v;
#pragma unroll
    for (int e = 0; e < 8; ++e) v[e] = tile[8*u + e][nl];
    size_t byte = (size_t)(b*NPIX + n)*512 + (size_t)((cu ^ (n & 7)) << 4);
    *(f16x8*)(xT + byte) = v;
  }
}

// ---------------- K3: K/V at subsampled pixels -> 32x32-frag-linear chunks ----------------
__global__ __launch_bounds__(256) void compute_kv(
    const char* __restrict__ xT, const f16* __restrict__ WkF, const f16* __restrict__ WvF,
    const float* __restrict__ bk2, const float* __restrict__ bv2,
    char* __restrict__ kB, char* __restrict__ vB) {
  int ch = blockIdx.x;            // key tile (32 keys)
  int m0 = ch * 32;
  int b = blockIdx.y;
  int tid = threadIdx.x;
  int w = tid >> 6, lane = tid & 63, l15 = lane & 15, q = lane >> 4;
  size_t chbase = (size_t)(b*32 + ch)*16384;

  const char* xrow[2]; int xn7[2];
#pragma unroll
  for (int mt2 = 0; mt2 < 2; ++mt2) {
    int m = m0 + 16*mt2 + l15;
    int n = 288*(m >> 5) + 3*(m & 31);   // subsampled pixel index
    xrow[mt2] = xT + (size_t)(b*NPIX + n)*512;
    xn7[mt2] = n & 7;
  }
  // frag-linear weight bases (coalesced 1KB frag loads)
  const char* wkf = (const char*)WkF + (size_t)lane*16;
  const char* wvf = (const char*)WvF + (size_t)lane*16;

  f32x4 accK[2][4] = {};
  f32x4 accV[4][2] = {};
  for (int ks = 0; ks < 8; ++ks) {
    f16x8 am[2], wk[4], wv[4];
#pragma unroll
    for (int mt2 = 0; mt2 < 2; ++mt2)
      am[mt2] = *(const f16x8*)(xrow[mt2] + (((q + 4*ks) ^ xn7[mt2]) << 4));
#pragma unroll
    for (int t = 0; t < 4; ++t) {
      wk[t] = *(const f16x8*)(wkf + (size_t)((4*w + t)*8 + ks)*1024);
      wv[t] = *(const f16x8*)(wvf + (size_t)((4*w + t)*8 + ks)*1024);
    }
#pragma unroll
    for (int mt2 = 0; mt2 < 2; ++mt2)
#pragma unroll
      for (int ot = 0; ot < 4; ++ot) {
        accK[mt2][ot] = mfma16(am[mt2], wk[ot], accK[mt2][ot]);   // D[m][o]
        accV[ot][mt2] = mfma16(wv[ot], am[mt2], accV[ot][mt2]);   // D[c][m]
      }
  }
  // K writes: keyrel=16mt2+4q+r, cin=64w+16ot+l15
#pragma unroll
  for (int mt2 = 0; mt2 < 2; ++mt2)
#pragma unroll
    for (int ot = 0; ot < 4; ++ot) {
      int cin = 64*w + 16*ot + l15;
      float bo = bk2[cin];
      size_t fb = chbase + (size_t)(cin >> 4)*1024 + (size_t)(((cin >> 3) & 1)*32)*16 + (cin & 7)*2;
#pragma unroll
      for (int r = 0; r < 4; ++r) {
        int keyrel = 16*mt2 + 4*q + r;
        *(f16*)(kB + fb + (size_t)keyrel*16) = (f16)(accK[mt2][ot][r] + bo);
      }
    }
  // V writes: c=64w+16ct+4q+r, keyrel=16mt2+l15
#pragma unroll
  for (int ct = 0; ct < 4; ++ct) {
    f32x4 bv4 = *(const f32x4*)(bv2 + 64*w + 16*ct + 4*q);
#pragma unroll
    for (int mt2 = 0; mt2 < 2; ++mt2) {
#pragma unroll
      for (int r = 0; r < 4; ++r) {
        int c = 64*w + 16*ct + 4*q + r;
        size_t byte = chbase + (size_t)(2*(c >> 5) + mt2)*1024
                    + (size_t)((l15 >> 3)*32 + (c & 31))*16 + (l15 & 7)*2;
        *(f16*)(vB + byte) = (f16)(accV[ct][mt2][r] + bv4[r]);
      }
    }
  }
}

// ---------------- K4: attention, swapped-QK 32x32, split QK chains ----------------
// R16 best-known configuration: 4 waves x 32 rows, 576 blocks, K/V dbuf 64KB,
// counted vmcnt(8), SA/SB dual 8-deep QK chains.
__global__ __launch_bounds__(256, 2) void attention(
    const char* __restrict__ xT, const f16* __restrict__ WqF, const float* __restrict__ bq,
    const char* __restrict__ kB, const char* __restrict__ vB,
    const float* __restrict__ xg, const float* __restrict__ gamma_p,
    float* __restrict__ out) {
  __shared__ char lds[65536];    // [2][ K 16KB | V 16KB ]

  int bid = blockIdx.x;
  int b = bid & 7;               // XCD-bijective: 576 = 8*72
  int tile = bid >> 3;
  int tid = threadIdx.x;
  int w = tid >> 6, lane = tid & 63, l31 = lane & 31, hh = lane >> 5;
  int n0w = tile*128 + w*32;     // this wave's q-row base
  int lane16 = lane * 16;

  const char* kBb = kB + (size_t)b*524288;
  const char* vBb = vB + (size_t)b*524288;

  // ---- stage K0/V0 early (hidden under phase A) ----
  {
    int so = tid * 16;
#pragma unroll
    for (int r = 0; r < 4; ++r) stage16(kBb + so + r*4096, lds + so + r*4096);
#pragma unroll
    for (int r = 0; r < 4; ++r) stage16(vBb + so + r*4096, lds + 16384 + so + r*4096);
  }

  // ---- Phase A: per-wave Q build -> qf[16] B-frags (no LDS) ----
  f16x8 qf[16];
  {
    f16x8 xb[16];
    int n = n0w + l31;
    const char* xrow = xT + (size_t)(b*NPIX + n)*512;
    int n7 = n & 7;
#pragma unroll
    for (int s = 0; s < 16; ++s)
      xb[s] = *(const f16x8*)(xrow + (((2*s + hh) ^ n7) << 4));
#pragma unroll
    for (int ot = 0; ot < 8; ++ot) {
      f32x16 acc;
#pragma unroll
      for (int j = 0; j < 16; ++j) acc[j] = 0.f;
#pragma unroll
      for (int s = 0; s < 16; ++s) {
        f16x8 wa = *(const f16x8*)((const char*)WqF + (size_t)(ot*16 + s)*1024 + lane16);
        acc = mfma32(wa, xb[s], acc);    // D[o_rel][row=l31]
      }
#pragma unroll
      for (int i = 0; i < 4; ++i) {
        f32x4 bv4 = *(const f32x4*)(bq + 32*ot + 8*i + 4*hh);
#pragma unroll
        for (int j2 = 0; j2 < 4; ++j2) acc[4*i + j2] += bv4[j2];
      }
      qf[2*ot + 0] = pack_swap(acc[0], acc[1], acc[2], acc[3],
                               acc[4], acc[5], acc[6], acc[7], hh);
      qf[2*ot + 1] = pack_swap(acc[8], acc[9], acc[10], acc[11],
                               acc[12], acc[13], acc[14], acc[15], hh);
    }
  }

  // ---- main loop: 32 key-tiles, K/V double-buffer, counted vmcnt ----
  f32x16 O[8];
#pragma unroll
  for (int i = 0; i < 8; ++i)
#pragma unroll
    for (int j = 0; j < 16; ++j) O[i][j] = 0.f;
  float m_run = -3e38f, l_run = 0.f;

  for (int t = 0; t < 32; ++t) {
    char* curb = lds + ((t & 1) << 15);
    if (t < 31) {
      const char* ksrc = kBb + (size_t)(t + 1)*16384;
      const char* vsrc = vBb + (size_t)(t + 1)*16384;
      char* kd = lds + (((t + 1) & 1) << 15);
      int so = tid * 16;
#pragma unroll
      for (int r = 0; r < 4; ++r) stage16(ksrc + so + r*4096, kd + so + r*4096);
#pragma unroll
      for (int r = 0; r < 4; ++r) stage16(vsrc + so + r*4096, kd + 16384 + so + r*4096);
      WAIT_VM(8);
    } else {
      WAIT_VM(0);
    }
    S_BARRIER();

    // QK^T: two independent 8-deep chains (SA even frags, SB odd frags)
    f32x16 SA, SB;
#pragma unroll
    for (int j = 0; j < 16; ++j) { SA[j] = 0.f; SB[j] = 0.f; }
    __builtin_amdgcn_s_setprio(1);
#pragma unroll
    for (int s = 0; s < 8; ++s) {
      f16x8 kfa = *(const f16x8*)(curb + (2*s)*1024 + lane16);
      SA = mfma32(kfa, qf[2*s], SA);
      f16x8 kfb = *(const f16x8*)(curb + (2*s + 1)*1024 + lane16);
      SB = mfma32(kfb, qf[2*s + 1], SB);
    }
    __builtin_amdgcn_s_setprio(0);
    f32x16 S16;
#pragma unroll
    for (int j = 0; j < 16; ++j) S16[j] = SA[j] + SB[j];

    // lane-local softmax
    float mx = S16[0];
#pragma unroll
    for (int j = 1; j < 16; ++j) mx = fmaxf(mx, S16[j]);
    mx = fmaxf(mx, __shfl_xor(mx, 32));
    if (!__all(mx <= m_run + 8.0f)) {    // T13 defer-max
      float mn = fmaxf(m_run, mx);
      float al = __expf(m_run - mn);
      m_run = mn;
      l_run *= al;
#pragma unroll
      for (int i = 0; i < 8; ++i)
#pragma unroll
        for (int j = 0; j < 16; ++j) O[i][j] *= al;
    }
    float p[16];
    float ls = 0.f;
#pragma unroll
    for (int j = 0; j < 16; ++j) { p[j] = __expf(S16[j] - m_run); ls += p[j]; }
    l_run += ls;

    // P -> f16 B-frags (shfl-based half exchange)
    f16x8 pf0 = pack_swap(p[0], p[1], p[2], p[3], p[4], p[5], p[6], p[7], hh);
    f16x8 pf1 = pack_swap(p[8], p[9], p[10], p[11], p[12], p[13], p[14], p[15], hh);

    // PV: O[c][row] += V[key][c] * P[row][key]
    __builtin_amdgcn_s_setprio(1);
#pragma unroll
    for (int ct = 0; ct < 8; ++ct) {
      f16x8 vf0 = *(const f16x8*)(curb + 16384 + (ct*2 + 0)*1024 + lane16);
      O[ct] = mfma32(vf0, pf0, O[ct]);
      f16x8 vf1 = *(const f16x8*)(curb + 16384 + (ct*2 + 1)*1024 + lane16);
      O[ct] = mfma32(vf1, pf1, O[ct]);
    }
    __builtin_amdgcn_s_setprio(0);
    S_BARRIER();
  }

  // ---- epilogue: out = gamma*O/l + x ----
  l_run += __shfl_xor(l_run, 32);
  float inv = 1.0f / l_run;
  float g = gamma_p[0];
  int n = n0w + l31;
#pragma unroll
  for (int ct = 0; ct < 8; ++ct)
#pragma unroll
    for (int j = 0; j < 16; ++j) {
      int c = 32*ct + (j & 3) + 8*(j >> 2) + 4*hh;
      size_t idx = (size_t)(b*CDIM + c)*NPIX + n;
      out[idx] = g * (O[ct][j] * inv) + xg[idx];
    }
}

extern "C" void kernel_launch(void* const* d_in, const int* in_sizes, int n_in,
                              void* d_out, int out_size, void* d_ws, size_t ws_size,
                              hipStream_t stream) {
  (void)in_sizes; (void)n_in; (void)out_size; (void)ws_size;
  const float* x     = (const float*)d_in[0];
  const float* Wq    = (const float*)d_in[1];
  const float* bq    = (const float*)d_in[2];
  const float* Wk    = (const float*)d_in[3];
  const float* bk    = (const float*)d_in[4];
  const float* Wv    = (const float*)d_in[5];
  const float* bv    = (const float*)d_in[6];
  const float* Ws    = (const float*)d_in[7];
  const float* bs    = (const float*)d_in[8];
  const float* gamma = (const float*)d_in[9];

  char* ws = (char*)d_ws;
  float* bk2 = (float*)(ws);
  float* bv2 = (float*)(ws + 1024);
  char* xT   = ws + 4096;
  char* kB   = ws + 4096 + 37748736;
  char* vB   = kB + 4194304;
  f16* WqF   = (f16*)(vB + 4194304);
  f16* WkF   = WqF + 65536;
  f16* WvF   = WkF + 65536;

  prep_weights<<<256, 256, 0, stream>>>(Wq, Wk, bk, Wv, bv, Ws, bs, WqF, WkF, WvF, bk2, bv2);
  transpose_x<<<dim3(8, 288, 8), dim3(32, 8), 0, stream>>>(x, xT);
  compute_kv<<<dim3(32, 8), 256, 0, stream>>>(xT, WkF, WvF, bk2, bv2, kB, vB);
  attention<<<576, 256, 0, stream>>>(xT, WqF, bq, kB, vB, x, gamma, (float*)d_out);
}

// Round 19
// 188.111 us; speedup vs baseline: 1.7858x; 1.0384x over previous
//
#include <hip/hip_runtime.h>

typedef _Float16 f16;
typedef _Float16 f16x8 __attribute__((ext_vector_type(8)));
typedef __fp16 fp16x2 __attribute__((ext_vector_type(2)));
typedef float f32x4 __attribute__((ext_vector_type(4)));
typedef float f32x16 __attribute__((ext_vector_type(16)));

#define CDIM 256
#define NPIX 9216
#define NB 8

__device__ __forceinline__ f32x4 mfma16(f16x8 a, f16x8 b, f32x4 c) {
  return __builtin_amdgcn_mfma_f32_16x16x32_f16(a, b, c, 0, 0, 0);
}
__device__ __forceinline__ f32x16 mfma32(f16x8 a, f16x8 b, f32x16 c) {
  return __builtin_amdgcn_mfma_f32_32x32x16_f16(a, b, c, 0, 0, 0);
}
__device__ __forceinline__ f16x8 ld8(const f16* p) { return *(const f16x8*)p; }

__device__ __forceinline__ void stage16(const void* g, void* l) {
  __builtin_amdgcn_global_load_lds((const __attribute__((address_space(1))) unsigned int*)g,
                                   (__attribute__((address_space(3))) unsigned int*)l, 16, 0, 0);
}
#define S_BARRIER() do { asm volatile("" ::: "memory"); __builtin_amdgcn_s_barrier(); asm volatile("" ::: "memory"); } while (0)
#define WAIT_VM(N) do { asm volatile("s_waitcnt vmcnt(" #N ")" ::: "memory"); __builtin_amdgcn_sched_barrier(0); } while (0)

__device__ __forceinline__ unsigned pkrtz(float a, float b) {
  union { fp16x2 h; unsigned u; } cv;
  cv.h = __builtin_amdgcn_cvt_pkrtz(a, b);
  return cv.u;
}
union U8 { f16x8 v; unsigned u[4]; };

// Pack 8 f32 (reg-order of a 32x32 D half-group) into f16x8 B-frag word order,
// exchanging quads with the lane^32 partner via shfl (verified R9).
__device__ __forceinline__ f16x8 pack_swap(float v0, float v1, float v2, float v3,
                                           float v4, float v5, float v6, float v7,
                                           int hh) {
  unsigned a  = pkrtz(v0, v1);
  unsigned b2 = pkrtz(v2, v3);
  unsigned c2 = pkrtz(v4, v5);
  unsigned d2 = pkrtz(v6, v7);
  unsigned ex1 = __shfl_xor(hh ? a : c2, 32);
  unsigned ex2 = __shfl_xor(hh ? b2 : d2, 32);
  U8 r;
  r.u[0] = hh ? ex1 : a;
  r.u[1] = hh ? ex2 : b2;
  r.u[2] = hh ? c2 : ex1;
  r.u[3] = hh ? d2 : ex2;
  return r.v;
}

// 32x32x16 frags: A: lane(l31,h) holds A[row=l31][k=8h+e]; B: B[k=8h+e][col=l31].
// D: col=lane&31, row=(reg&3)+8*(reg>>2)+4*(lane>>5). 1KB lane-linear frags.
// 16x16x32 frags (K3): A: lane(l15,q) holds A[row=l15][k=8q+e]; B likewise.

// ---------------- K0: fused prep_weights + transpose_x ----------------
// blocks [0,256): weight fold (o = blockIdx.x).
// blocks [256,1408): transpose; idx = blockIdx.x-256: b = idx/144, n0 = (idx%144)*64.
__global__ __launch_bounds__(256) void prep_and_transpose(
    const float* __restrict__ x, char* __restrict__ xT,
    const float* __restrict__ Wq,
    const float* __restrict__ Wk, const float* __restrict__ bk,
    const float* __restrict__ Wv, const float* __restrict__ bv,
    const float* __restrict__ Ws, const float* __restrict__ bs,
    f16* __restrict__ WqF, f16* __restrict__ WkF, f16* __restrict__ WvF,
    float* __restrict__ bk2, float* __restrict__ bv2) {
  __shared__ f16 tile[32][66];   // stride 66: both phases bank-conflict-free
  if (blockIdx.x < 256) {
    // ---- weight fold ----
    int o = blockIdx.x, c = threadIdx.x;
    float ak = 0.f, av = 0.f;
    for (int i = 0; i < CDIM; ++i) {
      float w = Ws[o*CDIM + i];
      ak += w * Wk[i*CDIM + c];
      av += w * Wv[i*CDIM + c];
    }
    // WqF: 32x32-A layout (K4 Q build), verified R9:
    size_t qbyte = (size_t)((o >> 5)*16 + (c >> 4))*1024
                 + (size_t)(((c >> 3) & 1)*32 + (o & 31))*16 + (c & 7)*2;
    *(f16*)((char*)WqF + qbyte) = (f16)Wq[o*CDIM + c];
    // WkF/WvF: 16x16 frag-linear layout (K3):
    size_t fbyte = (size_t)((o >> 4)*8 + (c >> 5))*1024
                 + (size_t)(16*((c >> 3) & 3) + (o & 15))*16 + (c & 7)*2;
    *(f16*)((char*)WkF + fbyte) = (f16)ak;
    *(f16*)((char*)WvF + fbyte) = (f16)av;
    if (c == 0) {
      float sk = 0.f, sv = 0.f;
      for (int i = 0; i < CDIM; ++i) { float w = Ws[o*CDIM + i]; sk += w*bk[i]; sv += w*bv[i]; }
      bk2[o] = sk + bs[o];
      bv2[o] = sv + bs[o];
    }
  } else {
    // ---- transpose: 64 px x 256 ch per block ----
    int idx = blockIdx.x - 256;
    int b = idx / 144;
    int n0 = (idx % 144) * 64;
    int tid = threadIdx.x;
    int px = tid & 63, ch4 = tid >> 6;       // load indexing
    int row = tid >> 2, u = tid & 3;         // store indexing
    int n = n0 + row;
    size_t outrow = (size_t)(b*NPIX + n)*512;
#pragma unroll 1
    for (int ct = 0; ct < 8; ++ct) {
      int c0 = ct * 32;
#pragma unroll
      for (int j = 0; j < 8; ++j) {
        int cl = ch4 + 4*j;
        tile[cl][px] = (f16)x[(size_t)(b*CDIM + c0 + cl)*NPIX + n0 + px];
      }
      __syncthreads();
      f16x8 v;
#pragma unroll
      for (int e = 0; e < 8; ++e) v[e] = tile[8*u + e][row];
      int cu = ct*4 + u;
      *(f16x8*)(xT + outrow + (size_t)((cu ^ (n & 7)) << 4)) = v;
      __syncthreads();
    }
  }
}

// ---------------- K3: K/V at subsampled pixels -> 32x32-frag-linear chunks ----------------
__global__ __launch_bounds__(256) void compute_kv(
    const char* __restrict__ xT, const f16* __restrict__ WkF, const f16* __restrict__ WvF,
    const float* __restrict__ bk2, const float* __restrict__ bv2,
    char* __restrict__ kB, char* __restrict__ vB) {
  int ch = blockIdx.x;            // key tile (32 keys)
  int m0 = ch * 32;
  int b = blockIdx.y;
  int tid = threadIdx.x;
  int w = tid >> 6, lane = tid & 63, l15 = lane & 15, q = lane >> 4;
  size_t chbase = (size_t)(b*32 + ch)*16384;

  const char* xrow[2]; int xn7[2];
#pragma unroll
  for (int mt2 = 0; mt2 < 2; ++mt2) {
    int m = m0 + 16*mt2 + l15;
    int n = 288*(m >> 5) + 3*(m & 31);   // subsampled pixel index
    xrow[mt2] = xT + (size_t)(b*NPIX + n)*512;
    xn7[mt2] = n & 7;
  }
  const char* wkf = (const char*)WkF + (size_t)lane*16;
  const char* wvf = (const char*)WvF + (size_t)lane*16;

  f32x4 accK[2][4] = {};
  f32x4 accV[4][2] = {};
  for (int ks = 0; ks < 8; ++ks) {
    f16x8 am[2], wk[4], wv[4];
#pragma unroll
    for (int mt2 = 0; mt2 < 2; ++mt2)
      am[mt2] = *(const f16x8*)(xrow[mt2] + (((q + 4*ks) ^ xn7[mt2]) << 4));
#pragma unroll
    for (int t = 0; t < 4; ++t) {
      wk[t] = *(const f16x8*)(wkf + (size_t)((4*w + t)*8 + ks)*1024);
      wv[t] = *(const f16x8*)(wvf + (size_t)((4*w + t)*8 + ks)*1024);
    }
#pragma unroll
    for (int mt2 = 0; mt2 < 2; ++mt2)
#pragma unroll
      for (int ot = 0; ot < 4; ++ot) {
        accK[mt2][ot] = mfma16(am[mt2], wk[ot], accK[mt2][ot]);   // D[m][o]
        accV[ot][mt2] = mfma16(wv[ot], am[mt2], accV[ot][mt2]);   // D[c][m]
      }
  }
  // K writes: keyrel=16mt2+4q+r, cin=64w+16ot+l15
#pragma unroll
  for (int mt2 = 0; mt2 < 2; ++mt2)
#pragma unroll
    for (int ot = 0; ot < 4; ++ot) {
      int cin = 64*w + 16*ot + l15;
      float bo = bk2[cin];
      size_t fb = chbase + (size_t)(cin >> 4)*1024 + (size_t)(((cin >> 3) & 1)*32)*16 + (cin & 7)*2;
#pragma unroll
      for (int r = 0; r < 4; ++r) {
        int keyrel = 16*mt2 + 4*q + r;
        *(f16*)(kB + fb + (size_t)keyrel*16) = (f16)(accK[mt2][ot][r] + bo);
      }
    }
  // V writes: c=64w+16ct+4q+r, keyrel=16mt2+l15
#pragma unroll
  for (int ct = 0; ct < 4; ++ct) {
    f32x4 bv4 = *(const f32x4*)(bv2 + 64*w + 16*ct + 4*q);
#pragma unroll
    for (int mt2 = 0; mt2 < 2; ++mt2) {
#pragma unroll
      for (int r = 0; r < 4; ++r) {
        int c = 64*w + 16*ct + 4*q + r;
        size_t byte = chbase + (size_t)(2*(c >> 5) + mt2)*1024
                    + (size_t)((l15 >> 3)*32 + (c & 31))*16 + (l15 & 7)*2;
        *(f16*)(vB + byte) = (f16)(accV[ct][mt2][r] + bv4[r]);
      }
    }
  }
}

// ---------------- K4: attention, swapped-QK 32x32, split QK chains (R16 best) ----------------
__global__ __launch_bounds__(256, 2) void attention(
    const char* __restrict__ xT, const f16* __restrict__ WqF, const float* __restrict__ bq,
    const char* __restrict__ kB, const char* __restrict__ vB,
    const float* __restrict__ xg, const float* __restrict__ gamma_p,
    float* __restrict__ out) {
  __shared__ char lds[65536];    // [2][ K 16KB | V 16KB ]

  int bid = blockIdx.x;
  int b = bid & 7;               // XCD-bijective: 576 = 8*72
  int tile = bid >> 3;
  int tid = threadIdx.x;
  int w = tid >> 6, lane = tid & 63, l31 = lane & 31, hh = lane >> 5;
  int n0w = tile*128 + w*32;     // this wave's q-row base
  int lane16 = lane * 16;

  const char* kBb = kB + (size_t)b*524288;
  const char* vBb = vB + (size_t)b*524288;

  // ---- stage K0/V0 early (hidden under phase A) ----
  {
    int so = tid * 16;
#pragma unroll
    for (int r = 0; r < 4; ++r) stage16(kBb + so + r*4096, lds + so + r*4096);
#pragma unroll
    for (int r = 0; r < 4; ++r) stage16(vBb + so + r*4096, lds + 16384 + so + r*4096);
  }

  // ---- Phase A: per-wave Q build -> qf[16] B-frags (no LDS) ----
  f16x8 qf[16];
  {
    f16x8 xb[16];
    int n = n0w + l31;
    const char* xrow = xT + (size_t)(b*NPIX + n)*512;
    int n7 = n & 7;
#pragma unroll
    for (int s = 0; s < 16; ++s)
      xb[s] = *(const f16x8*)(xrow + (((2*s + hh) ^ n7) << 4));
#pragma unroll
    for (int ot = 0; ot < 8; ++ot) {
      f32x16 acc;
#pragma unroll
      for (int j = 0; j < 16; ++j) acc[j] = 0.f;
#pragma unroll
      for (int s = 0; s < 16; ++s) {
        f16x8 wa = *(const f16x8*)((const char*)WqF + (size_t)(ot*16 + s)*1024 + lane16);
        acc = mfma32(wa, xb[s], acc);    // D[o_rel][row=l31]
      }
#pragma unroll
      for (int i = 0; i < 4; ++i) {
        f32x4 bv4 = *(const f32x4*)(bq + 32*ot + 8*i + 4*hh);
#pragma unroll
        for (int j2 = 0; j2 < 4; ++j2) acc[4*i + j2] += bv4[j2];
      }
      qf[2*ot + 0] = pack_swap(acc[0], acc[1], acc[2], acc[3],
                               acc[4], acc[5], acc[6], acc[7], hh);
      qf[2*ot + 1] = pack_swap(acc[8], acc[9], acc[10], acc[11],
                               acc[12], acc[13], acc[14], acc[15], hh);
    }
  }

  // ---- main loop: 32 key-tiles, K/V double-buffer, counted vmcnt ----
  f32x16 O[8];
#pragma unroll
  for (int i = 0; i < 8; ++i)
#pragma unroll
    for (int j = 0; j < 16; ++j) O[i][j] = 0.f;
  float m_run = -3e38f, l_run = 0.f;

  for (int t = 0; t < 32; ++t) {
    char* curb = lds + ((t & 1) << 15);
    if (t < 31) {
      const char* ksrc = kBb + (size_t)(t + 1)*16384;
      const char* vsrc = vBb + (size_t)(t + 1)*16384;
      char* kd = lds + (((t + 1) & 1) << 15);
      int so = tid * 16;
#pragma unroll
      for (int r = 0; r < 4; ++r) stage16(ksrc + so + r*4096, kd + so + r*4096);
#pragma unroll
      for (int r = 0; r < 4; ++r) stage16(vsrc + so + r*4096, kd + 16384 + so + r*4096);
      WAIT_VM(8);
    } else {
      WAIT_VM(0);
    }
    S_BARRIER();

    // QK^T: two independent 8-deep chains (SA even frags, SB odd frags)
    f32x16 SA, SB;
#pragma unroll
    for (int j = 0; j < 16; ++j) { SA[j] = 0.f; SB[j] = 0.f; }
    __builtin_amdgcn_s_setprio(1);
#pragma unroll
    for (int s = 0; s < 8; ++s) {
      f16x8 kfa = *(const f16x8*)(curb + (2*s)*1024 + lane16);
      SA = mfma32(kfa, qf[2*s], SA);
      f16x8 kfb = *(const f16x8*)(curb + (2*s + 1)*1024 + lane16);
      SB = mfma32(kfb, qf[2*s + 1], SB);
    }
    __builtin_amdgcn_s_setprio(0);
    f32x16 S16;
#pragma unroll
    for (int j = 0; j < 16; ++j) S16[j] = SA[j] + SB[j];

    // lane-local softmax
    float mx = S16[0];
#pragma unroll
    for (int j = 1; j < 16; ++j) mx = fmaxf(mx, S16[j]);
    mx = fmaxf(mx, __shfl_xor(mx, 32));
    if (!__all(mx <= m_run + 8.0f)) {    // T13 defer-max
      float mn = fmaxf(m_run, mx);
      float al = __expf(m_run - mn);
      m_run = mn;
      l_run *= al;
#pragma unroll
      for (int i = 0; i < 8; ++i)
#pragma unroll
        for (int j = 0; j < 16; ++j) O[i][j] *= al;
    }
    float p[16];
    float ls = 0.f;
#pragma unroll
    for (int j = 0; j < 16; ++j) { p[j] = __expf(S16[j] - m_run); ls += p[j]; }
    l_run += ls;

    // P -> f16 B-frags (shfl-based half exchange)
    f16x8 pf0 = pack_swap(p[0], p[1], p[2], p[3], p[4], p[5], p[6], p[7], hh);
    f16x8 pf1 = pack_swap(p[8], p[9], p[10], p[11], p[12], p[13], p[14], p[15], hh);

    // PV: O[c][row] += V[key][c] * P[row][key]
    __builtin_amdgcn_s_setprio(1);
#pragma unroll
    for (int ct = 0; ct < 8; ++ct) {
      f16x8 vf0 = *(const f16x8*)(curb + 16384 + (ct*2 + 0)*1024 + lane16);
      O[ct] = mfma32(vf0, pf0, O[ct]);
      f16x8 vf1 = *(const f16x8*)(curb + 16384 + (ct*2 + 1)*1024 + lane16);
      O[ct] = mfma32(vf1, pf1, O[ct]);
    }
    __builtin_amdgcn_s_setprio(0);
    S_BARRIER();
  }

  // ---- epilogue: out = gamma*O/l + x ----
  l_run += __shfl_xor(l_run, 32);
  float inv = 1.0f / l_run;
  float g = gamma_p[0];
  int n = n0w + l31;
#pragma unroll
  for (int ct = 0; ct < 8; ++ct)
#pragma unroll
    for (int j = 0; j < 16; ++j) {
      int c = 32*ct + (j & 3) + 8*(j >> 2) + 4*hh;
      size_t idx = (size_t)(b*CDIM + c)*NPIX + n;
      out[idx] = g * (O[ct][j] * inv) + xg[idx];
    }
}

extern "C" void kernel_launch(void* const* d_in, const int* in_sizes, int n_in,
                              void* d_out, int out_size, void* d_ws, size_t ws_size,
                              hipStream_t stream) {
  (void)in_sizes; (void)n_in; (void)out_size; (void)ws_size;
  const float* x     = (const float*)d_in[0];
  const float* Wq    = (const float*)d_in[1];
  const float* bq    = (const float*)d_in[2];
  const float* Wk    = (const float*)d_in[3];
  const float* bk    = (const float*)d_in[4];
  const float* Wv    = (const float*)d_in[5];
  const float* bv    = (const float*)d_in[6];
  const float* Ws    = (const float*)d_in[7];
  const float* bs    = (const float*)d_in[8];
  const float* gamma = (const float*)d_in[9];

  char* ws = (char*)d_ws;
  float* bk2 = (float*)(ws);
  float* bv2 = (float*)(ws + 1024);
  char* xT   = ws + 4096;
  char* kB   = ws + 4096 + 37748736;
  char* vB   = kB + 4194304;
  f16* WqF   = (f16*)(vB + 4194304);
  f16* WkF   = WqF + 65536;
  f16* WvF   = WkF + 65536;

  prep_and_transpose<<<1408, 256, 0, stream>>>(x, xT, Wq, Wk, bk, Wv, bv, Ws, bs,
                                               WqF, WkF, WvF, bk2, bv2);
  compute_kv<<<dim3(32, 8), 256, 0, stream>>>(xT, WkF, WvF, bk2, bv2, kB, vB);
  attention<<<576, 256, 0, stream>>>(xT, WqF, bq, kB, vB, x, gamma, (float*)d_out);
}

// Round 20
// 186.575 us; speedup vs baseline: 1.8005x; 1.0082x over previous
//
#include <hip/hip_runtime.h>

typedef _Float16 f16;
typedef _Float16 f16x8 __attribute__((ext_vector_type(8)));
typedef __fp16 fp16x2 __attribute__((ext_vector_type(2)));
typedef float f32x4 __attribute__((ext_vector_type(4)));
typedef float f32x16 __attribute__((ext_vector_type(16)));

#define CDIM 256
#define NPIX 9216
#define NB 8

__device__ __forceinline__ f32x4 mfma16(f16x8 a, f16x8 b, f32x4 c) {
  return __builtin_amdgcn_mfma_f32_16x16x32_f16(a, b, c, 0, 0, 0);
}
__device__ __forceinline__ f32x16 mfma32(f16x8 a, f16x8 b, f32x16 c) {
  return __builtin_amdgcn_mfma_f32_32x32x16_f16(a, b, c, 0, 0, 0);
}
__device__ __forceinline__ f16x8 ld8(const f16* p) { return *(const f16x8*)p; }

__device__ __forceinline__ void stage16(const void* g, void* l) {
  __builtin_amdgcn_global_load_lds((const __attribute__((address_space(1))) unsigned int*)g,
                                   (__attribute__((address_space(3))) unsigned int*)l, 16, 0, 0);
}
#define S_BARRIER() do { asm volatile("" ::: "memory"); __builtin_amdgcn_s_barrier(); asm volatile("" ::: "memory"); } while (0)
#define WAIT_VM(N) do { asm volatile("s_waitcnt vmcnt(" #N ")" ::: "memory"); __builtin_amdgcn_sched_barrier(0); } while (0)

__device__ __forceinline__ unsigned pkrtz(float a, float b) {
  union { fp16x2 h; unsigned u; } cv;
  cv.h = __builtin_amdgcn_cvt_pkrtz(a, b);
  return cv.u;
}
union U8 { f16x8 v; unsigned u[4]; };

// Pack 8 f32 (reg-order of a 32x32 D half-group) into f16x8 B-frag word order,
// exchanging quads with the lane^32 partner via shfl (verified R9).
__device__ __forceinline__ f16x8 pack_swap(float v0, float v1, float v2, float v3,
                                           float v4, float v5, float v6, float v7,
                                           int hh) {
  unsigned a  = pkrtz(v0, v1);
  unsigned b2 = pkrtz(v2, v3);
  unsigned c2 = pkrtz(v4, v5);
  unsigned d2 = pkrtz(v6, v7);
  unsigned ex1 = __shfl_xor(hh ? a : c2, 32);
  unsigned ex2 = __shfl_xor(hh ? b2 : d2, 32);
  U8 r;
  r.u[0] = hh ? ex1 : a;
  r.u[1] = hh ? ex2 : b2;
  r.u[2] = hh ? c2 : ex1;
  r.u[3] = hh ? d2 : ex2;
  return r.v;
}

// 32x32x16 frags: A: lane(l31,h) holds A[row=l31][k=8h+e]; B: B[k=8h+e][col=l31].
// D: col=lane&31, row=(reg&3)+8*(reg>>2)+4*(lane>>5). 1KB lane-linear frags.
// 16x16x32 frags (K3): A: lane(l15,q) holds A[row=l15][k=8q+e]; B likewise.

// ---------------- K0: fused prep_weights + transpose_x (R19, verified) ----------------
__global__ __launch_bounds__(256) void prep_and_transpose(
    const float* __restrict__ x, char* __restrict__ xT,
    const float* __restrict__ Wq,
    const float* __restrict__ Wk, const float* __restrict__ bk,
    const float* __restrict__ Wv, const float* __restrict__ bv,
    const float* __restrict__ Ws, const float* __restrict__ bs,
    f16* __restrict__ WqF, f16* __restrict__ WkF, f16* __restrict__ WvF,
    float* __restrict__ bk2, float* __restrict__ bv2) {
  __shared__ f16 tile[32][66];   // stride 66: both phases bank-conflict-free
  if (blockIdx.x < 256) {
    // ---- weight fold ----
    int o = blockIdx.x, c = threadIdx.x;
    float ak = 0.f, av = 0.f;
    for (int i = 0; i < CDIM; ++i) {
      float w = Ws[o*CDIM + i];
      ak += w * Wk[i*CDIM + c];
      av += w * Wv[i*CDIM + c];
    }
    size_t qbyte = (size_t)((o >> 5)*16 + (c >> 4))*1024
                 + (size_t)(((c >> 3) & 1)*32 + (o & 31))*16 + (c & 7)*2;
    *(f16*)((char*)WqF + qbyte) = (f16)Wq[o*CDIM + c];
    size_t fbyte = (size_t)((o >> 4)*8 + (c >> 5))*1024
                 + (size_t)(16*((c >> 3) & 3) + (o & 15))*16 + (c & 7)*2;
    *(f16*)((char*)WkF + fbyte) = (f16)ak;
    *(f16*)((char*)WvF + fbyte) = (f16)av;
    if (c == 0) {
      float sk = 0.f, sv = 0.f;
      for (int i = 0; i < CDIM; ++i) { float w = Ws[o*CDIM + i]; sk += w*bk[i]; sv += w*bv[i]; }
      bk2[o] = sk + bs[o];
      bv2[o] = sv + bs[o];
    }
  } else {
    // ---- transpose: 64 px x 256 ch per block ----
    int idx = blockIdx.x - 256;
    int b = idx / 144;
    int n0 = (idx % 144) * 64;
    int tid = threadIdx.x;
    int px = tid & 63, ch4 = tid >> 6;       // load indexing
    int row = tid >> 2, u = tid & 3;         // store indexing
    int n = n0 + row;
    size_t outrow = (size_t)(b*NPIX + n)*512;
#pragma unroll 1
    for (int ct = 0; ct < 8; ++ct) {
      int c0 = ct * 32;
#pragma unroll
      for (int j = 0; j < 8; ++j) {
        int cl = ch4 + 4*j;
        tile[cl][px] = (f16)x[(size_t)(b*CDIM + c0 + cl)*NPIX + n0 + px];
      }
      __syncthreads();
      f16x8 v;
#pragma unroll
      for (int e = 0; e < 8; ++e) v[e] = tile[8*u + e][row];
      int cu = ct*4 + u;
      *(f16x8*)(xT + outrow + (size_t)((cu ^ (n & 7)) << 4)) = v;
      __syncthreads();
    }
  }
}

// ---------------- K3: K/V at subsampled pixels, role-split blocks ----------------
// grid (32, 8, 2): z=0 -> K production, z=1 -> V production. 512 blocks =
// 2 blocks/CU (vs 1 before) to hide single-wave latency.
__global__ __launch_bounds__(256) void compute_kv(
    const char* __restrict__ xT, const f16* __restrict__ WkF, const f16* __restrict__ WvF,
    const float* __restrict__ bk2, const float* __restrict__ bv2,
    char* __restrict__ kB, char* __restrict__ vB) {
  int ch = blockIdx.x;            // key tile (32 keys)
  int m0 = ch * 32;
  int b = blockIdx.y;
  int role = blockIdx.z;          // 0 = K, 1 = V
  int tid = threadIdx.x;
  int w = tid >> 6, lane = tid & 63, l15 = lane & 15, q = lane >> 4;
  size_t chbase = (size_t)(b*32 + ch)*16384;

  const char* xrow[2]; int xn7[2];
#pragma unroll
  for (int mt2 = 0; mt2 < 2; ++mt2) {
    int m = m0 + 16*mt2 + l15;
    int n = 288*(m >> 5) + 3*(m & 31);   // subsampled pixel index
    xrow[mt2] = xT + (size_t)(b*NPIX + n)*512;
    xn7[mt2] = n & 7;
  }

  if (role == 0) {
    // ---- K production ----
    const char* wkf = (const char*)WkF + (size_t)lane*16;
    f32x4 accK[2][4] = {};
    for (int ks = 0; ks < 8; ++ks) {
      f16x8 am[2], wk[4];
#pragma unroll
      for (int mt2 = 0; mt2 < 2; ++mt2)
        am[mt2] = *(const f16x8*)(xrow[mt2] + (((q + 4*ks) ^ xn7[mt2]) << 4));
#pragma unroll
      for (int t = 0; t < 4; ++t)
        wk[t] = *(const f16x8*)(wkf + (size_t)((4*w + t)*8 + ks)*1024);
#pragma unroll
      for (int mt2 = 0; mt2 < 2; ++mt2)
#pragma unroll
        for (int ot = 0; ot < 4; ++ot)
          accK[mt2][ot] = mfma16(am[mt2], wk[ot], accK[mt2][ot]);   // D[m][o]
    }
#pragma unroll
    for (int mt2 = 0; mt2 < 2; ++mt2)
#pragma unroll
      for (int ot = 0; ot < 4; ++ot) {
        int cin = 64*w + 16*ot + l15;
        float bo = bk2[cin];
        size_t fb = chbase + (size_t)(cin >> 4)*1024 + (size_t)(((cin >> 3) & 1)*32)*16 + (cin & 7)*2;
#pragma unroll
        for (int r = 0; r < 4; ++r) {
          int keyrel = 16*mt2 + 4*q + r;
          *(f16*)(kB + fb + (size_t)keyrel*16) = (f16)(accK[mt2][ot][r] + bo);
        }
      }
  } else {
    // ---- V production ----
    const char* wvf = (const char*)WvF + (size_t)lane*16;
    f32x4 accV[4][2] = {};
    for (int ks = 0; ks < 8; ++ks) {
      f16x8 am[2], wv[4];
#pragma unroll
      for (int mt2 = 0; mt2 < 2; ++mt2)
        am[mt2] = *(const f16x8*)(xrow[mt2] + (((q + 4*ks) ^ xn7[mt2]) << 4));
#pragma unroll
      for (int t = 0; t < 4; ++t)
        wv[t] = *(const f16x8*)(wvf + (size_t)((4*w + t)*8 + ks)*1024);
#pragma unroll
      for (int mt2 = 0; mt2 < 2; ++mt2)
#pragma unroll
        for (int ot = 0; ot < 4; ++ot)
          accV[ot][mt2] = mfma16(wv[ot], am[mt2], accV[ot][mt2]);   // D[c][m]
    }
#pragma unroll
    for (int ct = 0; ct < 4; ++ct) {
      f32x4 bv4 = *(const f32x4*)(bv2 + 64*w + 16*ct + 4*q);
#pragma unroll
      for (int mt2 = 0; mt2 < 2; ++mt2) {
#pragma unroll
        for (int r = 0; r < 4; ++r) {
          int c = 64*w + 16*ct + 4*q + r;
          size_t byte = chbase + (size_t)(2*(c >> 5) + mt2)*1024
                      + (size_t)((l15 >> 3)*32 + (c & 31))*16 + (l15 & 7)*2;
          *(f16*)(vB + byte) = (f16)(accV[ct][mt2][r] + bv4[r]);
        }
      }
    }
  }
}

// ---------------- K4: attention, swapped-QK 32x32, split QK chains (R16 best) ----------------
__global__ __launch_bounds__(256, 2) void attention(
    const char* __restrict__ xT, const f16* __restrict__ WqF, const float* __restrict__ bq,
    const char* __restrict__ kB, const char* __restrict__ vB,
    const float* __restrict__ xg, const float* __restrict__ gamma_p,
    float* __restrict__ out) {
  __shared__ char lds[65536];    // [2][ K 16KB | V 16KB ]

  int bid = blockIdx.x;
  int b = bid & 7;               // XCD-bijective: 576 = 8*72
  int tile = bid >> 3;
  int tid = threadIdx.x;
  int w = tid >> 6, lane = tid & 63, l31 = lane & 31, hh = lane >> 5;
  int n0w = tile*128 + w*32;     // this wave's q-row base
  int lane16 = lane * 16;

  const char* kBb = kB + (size_t)b*524288;
  const char* vBb = vB + (size_t)b*524288;

  // ---- stage K0/V0 early (hidden under phase A) ----
  {
    int so = tid * 16;
#pragma unroll
    for (int r = 0; r < 4; ++r) stage16(kBb + so + r*4096, lds + so + r*4096);
#pragma unroll
    for (int r = 0; r < 4; ++r) stage16(vBb + so + r*4096, lds + 16384 + so + r*4096);
  }

  // ---- Phase A: per-wave Q build -> qf[16] B-frags (no LDS) ----
  f16x8 qf[16];
  {
    f16x8 xb[16];
    int n = n0w + l31;
    const char* xrow = xT + (size_t)(b*NPIX + n)*512;
    int n7 = n & 7;
#pragma unroll
    for (int s = 0; s < 16; ++s)
      xb[s] = *(const f16x8*)(xrow + (((2*s + hh) ^ n7) << 4));
#pragma unroll
    for (int ot = 0; ot < 8; ++ot) {
      f32x16 acc;
#pragma unroll
      for (int j = 0; j < 16; ++j) acc[j] = 0.f;
#pragma unroll
      for (int s = 0; s < 16; ++s) {
        f16x8 wa = *(const f16x8*)((const char*)WqF + (size_t)(ot*16 + s)*1024 + lane16);
        acc = mfma32(wa, xb[s], acc);    // D[o_rel][row=l31]
      }
#pragma unroll
      for (int i = 0; i < 4; ++i) {
        f32x4 bv4 = *(const f32x4*)(bq + 32*ot + 8*i + 4*hh);
#pragma unroll
        for (int j2 = 0; j2 < 4; ++j2) acc[4*i + j2] += bv4[j2];
      }
      qf[2*ot + 0] = pack_swap(acc[0], acc[1], acc[2], acc[3],
                               acc[4], acc[5], acc[6], acc[7], hh);
      qf[2*ot + 1] = pack_swap(acc[8], acc[9], acc[10], acc[11],
                               acc[12], acc[13], acc[14], acc[15], hh);
    }
  }

  // ---- main loop: 32 key-tiles, K/V double-buffer, counted vmcnt ----
  f32x16 O[8];
#pragma unroll
  for (int i = 0; i < 8; ++i)
#pragma unroll
    for (int j = 0; j < 16; ++j) O[i][j] = 0.f;
  float m_run = -3e38f, l_run = 0.f;

  for (int t = 0; t < 32; ++t) {
    char* curb = lds + ((t & 1) << 15);
    if (t < 31) {
      const char* ksrc = kBb + (size_t)(t + 1)*16384;
      const char* vsrc = vBb + (size_t)(t + 1)*16384;
      char* kd = lds + (((t + 1) & 1) << 15);
      int so = tid * 16;
#pragma unroll
      for (int r = 0; r < 4; ++r) stage16(ksrc + so + r*4096, kd + so + r*4096);
#pragma unroll
      for (int r = 0; r < 4; ++r) stage16(vsrc + so + r*4096, kd + 16384 + so + r*4096);
      WAIT_VM(8);
    } else {
      WAIT_VM(0);
    }
    S_BARRIER();

    // QK^T: two independent 8-deep chains (SA even frags, SB odd frags)
    f32x16 SA, SB;
#pragma unroll
    for (int j = 0; j < 16; ++j) { SA[j] = 0.f; SB[j] = 0.f; }
    __builtin_amdgcn_s_setprio(1);
#pragma unroll
    for (int s = 0; s < 8; ++s) {
      f16x8 kfa = *(const f16x8*)(curb + (2*s)*1024 + lane16);
      SA = mfma32(kfa, qf[2*s], SA);
      f16x8 kfb = *(const f16x8*)(curb + (2*s + 1)*1024 + lane16);
      SB = mfma32(kfb, qf[2*s + 1], SB);
    }
    __builtin_amdgcn_s_setprio(0);
    f32x16 S16;
#pragma unroll
    for (int j = 0; j < 16; ++j) S16[j] = SA[j] + SB[j];

    // lane-local softmax
    float mx = S16[0];
#pragma unroll
    for (int j = 1; j < 16; ++j) mx = fmaxf(mx, S16[j]);
    mx = fmaxf(mx, __shfl_xor(mx, 32));
    if (!__all(mx <= m_run + 8.0f)) {    // T13 defer-max
      float mn = fmaxf(m_run, mx);
      float al = __expf(m_run - mn);
      m_run = mn;
      l_run *= al;
#pragma unroll
      for (int i = 0; i < 8; ++i)
#pragma unroll
        for (int j = 0; j < 16; ++j) O[i][j] *= al;
    }
    float p[16];
    float ls = 0.f;
#pragma unroll
    for (int j = 0; j < 16; ++j) { p[j] = __expf(S16[j] - m_run); ls += p[j]; }
    l_run += ls;

    // P -> f16 B-frags (shfl-based half exchange)
    f16x8 pf0 = pack_swap(p[0], p[1], p[2], p[3], p[4], p[5], p[6], p[7], hh);
    f16x8 pf1 = pack_swap(p[8], p[9], p[10], p[11], p[12], p[13], p[14], p[15], hh);

    // PV: O[c][row] += V[key][c] * P[row][key]
    __builtin_amdgcn_s_setprio(1);
#pragma unroll
    for (int ct = 0; ct < 8; ++ct) {
      f16x8 vf0 = *(const f16x8*)(curb + 16384 + (ct*2 + 0)*1024 + lane16);
      O[ct] = mfma32(vf0, pf0, O[ct]);
      f16x8 vf1 = *(const f16x8*)(curb + 16384 + (ct*2 + 1)*1024 + lane16);
      O[ct] = mfma32(vf1, pf1, O[ct]);
    }
    __builtin_amdgcn_s_setprio(0);
    S_BARRIER();
  }

  // ---- epilogue: out = gamma*O/l + x ----
  l_run += __shfl_xor(l_run, 32);
  float inv = 1.0f / l_run;
  float g = gamma_p[0];
  int n = n0w + l31;
#pragma unroll
  for (int ct = 0; ct < 8; ++ct)
#pragma unroll
    for (int j = 0; j < 16; ++j) {
      int c = 32*ct + (j & 3) + 8*(j >> 2) + 4*hh;
      size_t idx = (size_t)(b*CDIM + c)*NPIX + n;
      out[idx] = g * (O[ct][j] * inv) + xg[idx];
    }
}

extern "C" void kernel_launch(void* const* d_in, const int* in_sizes, int n_in,
                              void* d_out, int out_size, void* d_ws, size_t ws_size,
                              hipStream_t stream) {
  (void)in_sizes; (void)n_in; (void)out_size; (void)ws_size;
  const float* x     = (const float*)d_in[0];
  const float* Wq    = (const float*)d_in[1];
  const float* bq    = (const float*)d_in[2];
  const float* Wk    = (const float*)d_in[3];
  const float* bk    = (const float*)d_in[4];
  const float* Wv    = (const float*)d_in[5];
  const float* bv    = (const float*)d_in[6];
  const float* Ws    = (const float*)d_in[7];
  const float* bs    = (const float*)d_in[8];
  const float* gamma = (const float*)d_in[9];

  char* ws = (char*)d_ws;
  float* bk2 = (float*)(ws);
  float* bv2 = (float*)(ws + 1024);
  char* xT   = ws + 4096;
  char* kB   = ws + 4096 + 37748736;
  char* vB   = kB + 4194304;
  f16* WqF   = (f16*)(vB + 4194304);
  f16* WkF   = WqF + 65536;
  f16* WvF   = WkF + 65536;

  prep_and_transpose<<<1408, 256, 0, stream>>>(x, xT, Wq, Wk, bk, Wv, bv, Ws, bs,
                                               WqF, WkF, WvF, bk2, bv2);
  compute_kv<<<dim3(32, 8, 2), 256, 0, stream>>>(xT, WkF, WvF, bk2, bv2, kB, vB);
  attention<<<576, 256, 0, stream>>>(xT, WqF, bq, kB, vB, x, gamma, (float*)d_out);
}